// Round 3
// baseline (102.118 us; speedup 1.0000x reference)
//
#include <hip/hip_runtime.h>
#include <math.h>

// KANConv2D via bf16 MFMA 16x16x32, R9.
// R9: SINGLE ordinary kernel, no d_ws, no cvt pre-pass, no grid sync.
// Key insight: wave (nq,kh) lane l's B-fragment for K-step S is the
// contiguous 32B-aligned float8  ws[(nq*16+l&15)*2304 + S*32 + (l>>4)*8 .. +8],
// so each wave loads B directly from the fp32 weights (L2-resident, 663 KB)
// and converts to bf16 in-register (8x f2bf per step, ~24 VALU, hidden under
// MFMA across waves). Removes the cvt kernel launch + inter-kernel gap +
// d_ws round-trip from the critical path. (R8's cooperative fusion failed:
// hipLaunchCooperativeKernel silently did not execute under the harness.)
// GEMM structure = R7 (verified): 392 blocks (4 b x 14x7 tiles of 4x8 px,
// M=32), 512 thr = 8 waves, wave = (nq: oc quarter) x (kh: K half), M=32 per
// wave (two A-frags, two independent acc chains), cross-wave K reduction via
// LDS SoA, kh=0 waves do the epilogue.
// Frag maps (validated by passing R1/R6/R7 kernels / m89/m120):
//   A: m = lane&15 (+16 for frag1), k = (lane>>4)*8 + j
//   B: n = lane&15, k = (lane>>4)*8 + j
//   C/D: col = lane&15 = n, row = (lane>>4)*4 + reg = m (+16 for frag1).

typedef __attribute__((ext_vector_type(8))) short bf16x8;
typedef __attribute__((ext_vector_type(8))) float f32x8;
typedef __attribute__((ext_vector_type(4))) float f32x4;

#define MFMA16(a, b, c) __builtin_amdgcn_mfma_f32_16x16x32_bf16((a), (b), (c), 0, 0, 0)

__device__ __forceinline__ unsigned short f2bf(float f) {
    unsigned u = __builtin_bit_cast(unsigned, f);
    u = (u + 0x7fffu + ((u >> 16) & 1u)) >> 16;   // RNE
    return (unsigned short)u;
}

__device__ __forceinline__ bf16x8 cvt8(f32x8 w) {
    bf16x8 r;
    #pragma unroll
    for (int j = 0; j < 8; ++j) r[j] = (short)f2bf(w[j]);
    return r;
}

__device__ __forceinline__ void eval_bases(float v, float bs[8]) {
    #pragma unroll
    for (int i = 0; i < 8; ++i) bs[i] = 0.0f;
    // knots: t_g = (g-3)*0.4 - 1, support [-2.2, 2.2)
    float t = (v + 2.2f) * 2.5f;
    if (t >= 0.0f && t < 11.0f) {
        int j = (int)t;
        if (j > 10) j = 10;
        float knot = (float)(j - 3) * 0.4f - 1.0f;
        float u  = (v - knot) * 2.5f;
        float um = 1.0f - u;
        float u2 = u * u, u3 = u2 * u;
        const float s6 = 1.0f / 6.0f;
        float w0 = um * um * um * s6;
        float w1 = (3.0f * u3 - 6.0f * u2 + 4.0f) * s6;
        float w2 = (-3.0f * u3 + 3.0f * u2 + 3.0f * u + 1.0f) * s6;
        float w3 = u3 * s6;
        int i0 = j - 3;
        if (i0 >= 0)               bs[i0]     = w0;
        if (i0 + 1 >= 0 && i0 < 7) bs[i0 + 1] = w1;
        if (i0 + 2 >= 0 && i0 < 6) bs[i0 + 2] = w2;
        if (i0 + 3 <= 7)           bs[i0 + 3] = w3;
    }
}

__global__ __launch_bounds__(512)
void kan_mfma_kernel(const float* __restrict__ x,
                     const float* __restrict__ wb,
                     const float* __restrict__ ws,
                     const float* __restrict__ sc,
                     float* __restrict__ out) {
    __shared__ unsigned short smem[24832];   // 49664 B -> 3 blocks/CU (LDS cap)
    unsigned short* sb    = smem;            // [32][60][8] = 15360 ushorts
    unsigned short* patch = smem + 15360;    // [32][296]   = 9472 ushorts

    const int tid = threadIdx.x;
    const int bx  = blockIdx.x;              // 0..391
    const int b   = bx / 98;
    const int r   = bx - b * 98;
    const int ty  = r / 7;
    const int tx  = r - ty * 7;
    const int h0  = ty * 4, w0 = tx * 8;

    const int lane = tid & 63;
    const int wv   = tid >> 6;        // 0..7
    const int nq   = wv & 3;          // oc quarter (16 oc)
    const int kh   = wv >> 2;         // K half (0: first, 1: second)
    const int ml   = lane & 15;       // A row (frag0) / B,C col (oc)
    const int kg   = lane >> 4;       // k-group 0..3 within k32 step
    const int py0  = ml >> 3, px0 = ml & 7;   // frag0 pixel (rows 0..15)

    // ---- phase 1: batch 4 independent x loads, eval bases, store + scatter ----
    float vv[4];
    #pragma unroll
    for (int j = 0; j < 4; ++j) {
        int i = tid + j * 512;        // 0..2047
        float val = 0.0f;
        if (i < 1920) {
            int c  = i / 60;
            int hp = i - c * 60;
            int hy = hp / 10;
            int hx = hp - hy * 10;
            int hh = h0 + hy - 1, ww = w0 + hx - 1;
            if ((unsigned)hh < 56u && (unsigned)ww < 56u)
                val = x[((b * 32 + c) * 56 + hh) * 56 + ww];
        }
        vv[j] = val;
    }
    #pragma unroll
    for (int j = 0; j < 4; ++j) {
        int i = tid + j * 512;
        if (i < 1920) {
            int c  = i / 60;
            int hp = i - c * 60;
            int hy = hp / 10;
            int hx = hp - hy * 10;
            float bs[8];
            eval_bases(vv[j], bs);
            bf16x8 pk;
            #pragma unroll
            for (int j2 = 0; j2 < 8; ++j2) pk[j2] = (short)f2bf(bs[j2]);
            *reinterpret_cast<bf16x8*>(&sb[i * 8]) = pk;
            // scatter x into patch: halo (hy,hx) -> m=(hy-dkh)*8+(hx-dkw), k=c*9+dkh*3+dkw
            unsigned short xb = f2bf(vv[j]);
            #pragma unroll
            for (int dkh = 0; dkh < 3; ++dkh) {
                int py = hy - dkh;
                if ((unsigned)py < 4u) {
                    #pragma unroll
                    for (int dkw = 0; dkw < 3; ++dkw) {
                        int px = hx - dkw;
                        if ((unsigned)px < 8u)
                            patch[(py * 8 + px) * 296 + c * 9 + dkh * 3 + dkw] = xb;
                    }
                }
            }
        }
    }
    __syncthreads();

    // spline A offsets (ushort units): step S = 9g+u reads p = 4S + kg
    //   -> c = 4g + (4u+kg)/9, tap = (4u+kg)%9.  aoff is g-independent.
    // frag1 (rows 16..31) = frag0 offset + 2 halo rows = +160 ushorts.
    int aoff[9];
    #pragma unroll
    for (int u = 0; u < 9; ++u) {
        int tt  = 4 * u + kg;         // 0..35
        int dc  = tt / 9;
        int tap = tt - dc * 9;
        int th  = tap / 3;
        int tw  = tap - th * 3;
        aoff[u] = (dc * 60 + (py0 + th) * 10 + (px0 + tw)) * 8;
    }

    f32x4 accS0 = {0.f, 0.f, 0.f, 0.f};
    f32x4 accS1 = {0.f, 0.f, 0.f, 0.f};
    f32x4 accB0 = {0.f, 0.f, 0.f, 0.f};
    f32x4 accB1 = {0.f, 0.f, 0.f, 0.f};

    // ---- spline GEMM: this wave's 36 k32-steps (S = kh*36 + g*9 + u) ----
    // B direct from fp32 ws: lane reads float8 at oc*2304 + S*32 + kg*8.
    const float* wp = ws + (nq * 16 + ml) * 2304 + kh * 1152 + kg * 8;
    int cbase = kh * 4 * 1920;        // g starts at 4*kh: 4 channels * 480 ushorts each
    for (int g = 0; g < 4; ++g) {
        #pragma unroll
        for (int u = 0; u < 9; ++u) {
            f32x8 w8 = *reinterpret_cast<const f32x8*>(wp + (g * 9 + u) * 32);
            bf16x8 a0 = *reinterpret_cast<const bf16x8*>(&sb[cbase + aoff[u]]);
            bf16x8 a1 = *reinterpret_cast<const bf16x8*>(&sb[cbase + aoff[u] + 160]);
            bf16x8 bw = cvt8(w8);
            accS0 = MFMA16(a0, bw, accS0);
            accS1 = MFMA16(a1, bw, accS1);
        }
        cbase += 1920;
    }

    // ---- base GEMM: steps s in kh=0 -> 0..4, kh=1 -> 5..8 ----
    {
        const unsigned short* ap0 = patch + ml * 296 + kg * 8;
        const unsigned short* ap1 = ap0 + 16 * 296;
        const float* wbp = wb + (nq * 16 + ml) * 288 + kg * 8;
        const int sbeg = kh ? 5 : 0;
        const int send = kh ? 9 : 5;
        for (int s = sbeg; s < send; ++s) {
            f32x8 w8 = *reinterpret_cast<const f32x8*>(wbp + s * 32);
            bf16x8 a0 = *reinterpret_cast<const bf16x8*>(ap0 + s * 32);
            bf16x8 a1 = *reinterpret_cast<const bf16x8*>(ap1 + s * 32);
            bf16x8 bw = cvt8(w8);
            accB0 = MFMA16(a0, bw, accB0);
            accB1 = MFMA16(a1, bw, accB1);
        }
    }

    // ---- cross-wave K reduction via LDS (SoA: [16 words][260], conflict-free) ----
    __syncthreads();                               // all sb/patch reads done
    float* red = reinterpret_cast<float*>(smem);   // 16*260*4 = 16640 B, inside dead sb
    const int idx = nq * 64 + lane;                // 0..255, same for the kh pair
    if (kh) {
        #pragma unroll
        for (int w = 0; w < 4; ++w) red[(0  + w) * 260 + idx] = accS0[w];
        #pragma unroll
        for (int w = 0; w < 4; ++w) red[(4  + w) * 260 + idx] = accS1[w];
        #pragma unroll
        for (int w = 0; w < 4; ++w) red[(8  + w) * 260 + idx] = accB0[w];
        #pragma unroll
        for (int w = 0; w < 4; ++w) red[(12 + w) * 260 + idx] = accB1[w];
    }
    __syncthreads();
    if (!kh) {
        #pragma unroll
        for (int w = 0; w < 4; ++w) accS0[w] += red[(0  + w) * 260 + idx];
        #pragma unroll
        for (int w = 0; w < 4; ++w) accS1[w] += red[(4  + w) * 260 + idx];
        #pragma unroll
        for (int w = 0; w < 4; ++w) accB0[w] += red[(8  + w) * 260 + idx];
        #pragma unroll
        for (int w = 0; w < 4; ++w) accB1[w] += red[(12 + w) * 260 + idx];

        // ---- epilogue: C/D row = kg*4 + reg (+16 for frag1), col = ml = oc ----
        const int oc  = nq * 16 + ml;
        const float scv = sc[oc];
        #pragma unroll
        for (int f = 0; f < 2; ++f) {
            const int rowb = f * 16 + kg * 4;      // regs 0..3 share py
            const int py   = rowb >> 3;
            const int pxb  = rowb & 7;             // 0 or 4
            float* ob = out + ((b * 64 + oc) * 56 + h0 + py) * 56 + w0 + pxb;
            f32x4 aB = f ? accB1 : accB0;
            f32x4 aS = f ? accS1 : accS0;
            f32x4 res;
            #pragma unroll
            for (int reg = 0; reg < 4; ++reg) {
                float bv = aB[reg];
                float si = bv / (1.0f + __expf(-bv));
                res[reg] = si + scv * aS[reg];
            }
            *reinterpret_cast<f32x4*>(ob) = res;
        }
    }
}

extern "C" void kernel_launch(void* const* d_in, const int* in_sizes, int n_in,
                              void* d_out, int out_size, void* d_ws, size_t ws_size,
                              hipStream_t stream) {
    const float* x  = (const float*)d_in[0];   // (4,32,56,56)
    const float* wb = (const float*)d_in[1];   // (64,32,3,3)
    const float* ws = (const float*)d_in[2];   // (64,288,8)
    const float* sc = (const float*)d_in[3];   // (64,)
    float* out = (float*)d_out;                // (4,64,56,56)

    kan_mfma_kernel<<<392, 512, 0, stream>>>(x, wb, ws, sc, out);
}

// Round 4
// 73.174 us; speedup vs baseline: 1.3955x; 1.3955x over previous
//
#include <hip/hip_runtime.h>
#include <math.h>

// KANConv2D via bf16 MFMA 16x16x32, R10.
// R10: M=64 tiles to halve L2 B-stream traffic (231 -> 115 MB), scatter-free
// phase 1 via tap-major base-weight K-reorder, 196 blocks (one per CU).
// - cvt kernel pre-swizzles fp32 weights -> bf16 MFMA B-frag streams in d_ws
//   (d_ws poison fill is fixed harness overhead regardless of use — R9 proved).
// - Main: 196 blocks (4 b x 7x7 tiles of 8x8 px, M=64), 512 thr = 8 waves:
//   wave = (nq 0..3: oc quarter of 16) x (kh 0..1: K half). Each wave: 4
//   A-frags (16 rows each) x 36 k32-steps, 8 f32x4 accs; cross-wave K
//   reduction via LDS SoA; kh=0 waves do the epilogue.
// - Base conv uses k-order k = tap*32 + c (tap-major): A-frag j-dim = 8
//   consecutive CHANNELS at one spatial pos -> read raw-x halo xh[hp][c]
//   directly, no im2col scatter. Spline k-order unchanged (p*8 + basis).
// Frag maps (validated by passing R1/R6/R7 kernels / m89/m120):
//   A: m = lane&15 (+16f for frag f), k = (lane>>4)*8 + j
//   B: n = lane&15, k = (lane>>4)*8 + j
//   C/D: col = lane&15 = n, row = (lane>>4)*4 + reg (+16f for frag f).

typedef __attribute__((ext_vector_type(8))) short bf16x8;
typedef __attribute__((ext_vector_type(4))) float f32x4;

#define MFMA16(a, b, c) __builtin_amdgcn_mfma_f32_16x16x32_bf16((a), (b), (c), 0, 0, 0)

__device__ __forceinline__ unsigned short f2bf(float f) {
    unsigned u = __builtin_bit_cast(unsigned, f);
    u = (u + 0x7fffu + ((u >> 16) & 1u)) >> 16;   // RNE
    return (unsigned short)u;
}

__device__ __forceinline__ void eval_bases(float v, float bs[8]) {
    #pragma unroll
    for (int i = 0; i < 8; ++i) bs[i] = 0.0f;
    // knots: t_g = (g-3)*0.4 - 1, support [-2.2, 2.2)
    float t = (v + 2.2f) * 2.5f;
    if (t >= 0.0f && t < 11.0f) {
        int j = (int)t;
        if (j > 10) j = 10;
        float knot = (float)(j - 3) * 0.4f - 1.0f;
        float u  = (v - knot) * 2.5f;
        float um = 1.0f - u;
        float u2 = u * u, u3 = u2 * u;
        const float s6 = 1.0f / 6.0f;
        float w0 = um * um * um * s6;
        float w1 = (3.0f * u3 - 6.0f * u2 + 4.0f) * s6;
        float w2 = (-3.0f * u3 + 3.0f * u2 + 3.0f * u + 1.0f) * s6;
        float w3 = u3 * s6;
        int i0 = j - 3;
        if (i0 >= 0)               bs[i0]     = w0;
        if (i0 + 1 >= 0 && i0 < 7) bs[i0 + 1] = w1;
        if (i0 + 2 >= 0 && i0 < 6) bs[i0 + 2] = w2;
        if (i0 + 3 <= 7)           bs[i0 + 3] = w3;
    }
}

// ---- pre-kernel: fp32 weights -> bf16 B-frag streams ----
// wst (spline, k = p*8 + basis, unchanged):
//   wst[((nq*72+S)*64+l)*8+j] = ws[(nq*16+(l&15))*2304 + S*32 + (l>>4)*8 + j]
// wbt (base, NEW tap-major k = tap*32 + c):
//   wbt[((nq*9+s)*64+l)*8+j]  = wb[(nq*16+(l&15))*288 + ((l>>4)*8+j)*9 + s]
__global__ __launch_bounds__(256)
void cvt_swz_kernel(const float* __restrict__ ws, const float* __restrict__ wb,
                    unsigned short* __restrict__ wst, unsigned short* __restrict__ wbt) {
    int i = blockIdx.x * 256 + threadIdx.x;
    if (i < 147456) {
        int j = i & 7, l = (i >> 3) & 63, t = i >> 9;   // t 0..287
        int S = t % 72, nq = t / 72;
        int oc = nq * 16 + (l & 15);
        int k  = S * 32 + (l >> 4) * 8 + j;
        wst[i] = f2bf(ws[oc * 2304 + k]);
    } else {
        int i2 = i - 147456;
        if (i2 < 18432) {
            int j = i2 & 7, l = (i2 >> 3) & 63, t = i2 >> 9;  // t 0..35
            int s = t % 9, nq = t / 9;
            int oc = nq * 16 + (l & 15);
            int c  = (l >> 4) * 8 + j;
            wbt[i2] = f2bf(wb[oc * 288 + c * 9 + s]);
        }
    }
}

__global__ __launch_bounds__(512)
void kan_mfma_kernel(const float* __restrict__ x,
                     const float* __restrict__ sc,
                     const unsigned short* __restrict__ wst,
                     const unsigned short* __restrict__ wbt,
                     float* __restrict__ out) {
    // sb: bases [c 0..31][hp 0..99][8]   = 25600 us (51200 B)
    // xh: raw x [hp 0..99][40: 32 c+pad] =  4000 us ( 8000 B)  total 59200 B
    __shared__ unsigned short smem[29600];
    unsigned short* sb = smem;
    unsigned short* xh = smem + 25600;

    const int tid = threadIdx.x;
    const int bx  = blockIdx.x;              // 0..195
    const int b   = bx / 49;
    const int r   = bx - b * 49;
    const int ty  = r / 7;
    const int tx  = r - ty * 7;
    const int h0  = ty * 8, w0 = tx * 8;

    const int lane = tid & 63;
    const int wv   = tid >> 6;        // 0..7
    const int nq   = wv & 3;          // oc quarter (16 oc)
    const int kh   = wv >> 2;         // K half
    const int ml   = lane & 15;       // A row within frag / B,C col (oc)
    const int kg   = lane >> 4;       // k-group 0..3 within k32 step
    const int py0  = ml >> 3, px0 = ml & 7;   // frag-0 pixel (rows 0..15)

    // ---- phase 1: 3200 halo elems (10x10x32), batched loads, 1 store each ----
    float vv[7];
    #pragma unroll
    for (int j = 0; j < 7; ++j) {
        int i = tid + j * 512;        // 0..3583
        float val = 0.0f;
        if (i < 3200) {
            int c  = i / 100;
            int hp = i - c * 100;
            int hy = hp / 10;
            int hx = hp - hy * 10;
            int hh = h0 + hy - 1, ww = w0 + hx - 1;
            if ((unsigned)hh < 56u && (unsigned)ww < 56u)
                val = x[((b * 32 + c) * 56 + hh) * 56 + ww];
        }
        vv[j] = val;
    }
    #pragma unroll
    for (int j = 0; j < 7; ++j) {
        int i = tid + j * 512;
        if (i < 3200) {
            int c  = i / 100;
            int hp = i - c * 100;
            float bs[8];
            eval_bases(vv[j], bs);
            bf16x8 pk;
            #pragma unroll
            for (int j2 = 0; j2 < 8; ++j2) pk[j2] = (short)f2bf(bs[j2]);
            *reinterpret_cast<bf16x8*>(&sb[i * 8]) = pk;   // i = c*100+hp
            xh[hp * 40 + c] = f2bf(vv[j]);
        }
    }
    __syncthreads();

    // spline A offsets (ushort units): step S reads p = 4S + kg
    //   -> dc = (4u+kg)/9 within the g-quad, tap = (4u+kg)%9.
    // frag f (rows 16f..16f+15) = frag0 offset + 2f rows = +f*160 ushorts.
    int aoff[9];
    #pragma unroll
    for (int u = 0; u < 9; ++u) {
        int tt  = 4 * u + kg;         // 0..35
        int dc  = tt / 9;
        int tap = tt - dc * 9;
        int th  = tap / 3;
        int tw  = tap - th * 3;
        aoff[u] = (dc * 100 + (py0 + th) * 10 + (px0 + tw)) * 8;
    }

    f32x4 aS[4] = {{0,0,0,0},{0,0,0,0},{0,0,0,0},{0,0,0,0}};
    f32x4 aB[4] = {{0,0,0,0},{0,0,0,0},{0,0,0,0},{0,0,0,0}};

    // ---- spline GEMM: this wave's 36 k32-steps (global S = kh*36 + g*9 + u) ----
    const unsigned short* bp = wst + ((nq * 72 + kh * 36) * 64 + lane) * 8;
    int cbase = kh * 12800;           // 4kh channel-quads * 3200 ushorts
    for (int g = 0; g < 4; ++g) {
        #pragma unroll
        for (int u = 0; u < 9; ++u) {
            bf16x8 bw = *reinterpret_cast<const bf16x8*>(bp + (g * 9 + u) * 512);
            #pragma unroll
            for (int f = 0; f < 4; ++f) {
                bf16x8 a = *reinterpret_cast<const bf16x8*>(&sb[cbase + aoff[u] + f * 160]);
                aS[f] = MFMA16(a, bw, aS[f]);
            }
        }
        cbase += 3200;
    }

    // ---- base GEMM (tap-major): steps s: kh=0 -> 0..4, kh=1 -> 5..8 ----
    {
        const unsigned short* bbp = wbt + (nq * 9 * 64 + lane) * 8;
        const int sbeg = kh ? 5 : 0;
        const int send = kh ? 9 : 5;
        for (int s = sbeg; s < send; ++s) {
            int th = (s * 11) >> 5;           // s/3 for s in 0..8
            int tw = s - 3 * th;
            bf16x8 bw = *reinterpret_cast<const bf16x8*>(bbp + s * 512);
            int xa = ((py0 + th) * 10 + (px0 + tw)) * 40 + kg * 8;
            #pragma unroll
            for (int f = 0; f < 4; ++f) {     // frag f = +2 rows = +800 us
                bf16x8 a = *reinterpret_cast<const bf16x8*>(&xh[xa + f * 800]);
                aB[f] = MFMA16(a, bw, aB[f]);
            }
        }
    }

    // ---- cross-wave K reduction via LDS (SoA: [32 words][260], conflict-free) ----
    __syncthreads();                               // all sb/xh reads done
    float* red = reinterpret_cast<float*>(smem);   // 32*260*4 = 33280 B
    const int idx = nq * 64 + lane;                // 0..255, same for the kh pair
    if (kh) {
        #pragma unroll
        for (int f = 0; f < 4; ++f)
            #pragma unroll
            for (int w = 0; w < 4; ++w) red[(f * 4 + w) * 260 + idx] = aS[f][w];
        #pragma unroll
        for (int f = 0; f < 4; ++f)
            #pragma unroll
            for (int w = 0; w < 4; ++w) red[((16 + f * 4) + w) * 260 + idx] = aB[f][w];
    }
    __syncthreads();
    if (!kh) {
        #pragma unroll
        for (int f = 0; f < 4; ++f)
            #pragma unroll
            for (int w = 0; w < 4; ++w) aS[f][w] += red[(f * 4 + w) * 260 + idx];
        #pragma unroll
        for (int f = 0; f < 4; ++f)
            #pragma unroll
            for (int w = 0; w < 4; ++w) aB[f][w] += red[((16 + f * 4) + w) * 260 + idx];

        // ---- epilogue: row m = f*16 + kg*4 + reg -> py = f*2+(kg>>1), px = (kg&1)*4+reg
        const int oc  = nq * 16 + ml;
        const float scv = sc[oc];
        #pragma unroll
        for (int f = 0; f < 4; ++f) {
            const int py  = f * 2 + (kg >> 1);
            const int pxb = (kg & 1) * 4;
            float* ob = out + ((b * 64 + oc) * 56 + h0 + py) * 56 + w0 + pxb;
            f32x4 res;
            #pragma unroll
            for (int reg = 0; reg < 4; ++reg) {
                float bv = aB[f][reg];
                float si = bv / (1.0f + __expf(-bv));
                res[reg] = si + scv * aS[f][reg];
            }
            *reinterpret_cast<f32x4*>(ob) = res;
        }
    }
}

extern "C" void kernel_launch(void* const* d_in, const int* in_sizes, int n_in,
                              void* d_out, int out_size, void* d_ws, size_t ws_size,
                              hipStream_t stream) {
    const float* x  = (const float*)d_in[0];   // (4,32,56,56)
    const float* wb = (const float*)d_in[1];   // (64,32,3,3)
    const float* ws = (const float*)d_in[2];   // (64,288,8)
    const float* sc = (const float*)d_in[3];   // (64,)
    float* out = (float*)d_out;                // (4,64,56,56)

    unsigned short* wst = (unsigned short*)d_ws;   // 147456 bf16
    unsigned short* wbt = wst + 147456;            // 18432 bf16

    cvt_swz_kernel<<<648, 256, 0, stream>>>(ws, wb, wst, wbt);
    kan_mfma_kernel<<<196, 512, 0, stream>>>(x, sc, wst, wbt, out);
}